// Round 1
// 12335.145 us; speedup vs baseline: 1.6153x; 1.6153x over previous
//
#include <hip/hip_runtime.h>
#include <math.h>

// GRU B=64, T=512, D=512, H=1024 fp32.
// Round 7: full restructure around rocprof evidence (MfmaUtil 1.2%, occ 4.6%,
// FETCH 23 MB/step == W re-streamed every step + P round-trip).
//  - W lives in REGISTERS: 256 blocks x 8 waves, each wave holds its 36 W frags
//    (144 VGPR) for its 16-col x 6-ks slice -> zero W traffic in steady state.
//  - No k-split across blocks -> no P partial arrays. Each block owns a 16x16
//    output tile over full k=1536; k split 8-way across waves, reduced in LDS.
//  - Recurrence is row-independent: 4 independent rb-chains (16 rows each),
//    each with its own 64-block grouped-atomic barrier (proven structure).
//  - h passes between steps as a 128 KB bf16 parity-double-buffered array.
//  - x frags for t+1 prefetched into dead registers mid-step (hidden latency).
// build_wsw / barrier atomics / MFMA frag maps / gru_h verbatim from R1-R6.
#define T_STEPS 512
#define Bb 64
#define Dd 512
#define Hh 1024
#define NBLK 256
#define GRP 8            // blocks per barrier sub-group (8 groups x 8 = 64 per rb-chain)

typedef __attribute__((ext_vector_type(8))) short short8;
typedef __attribute__((ext_vector_type(4))) float floatx4;

__device__ __forceinline__ unsigned short f2bf(float f) {
    unsigned u = __float_as_uint(f);
    unsigned r = u + 0x7fffu + ((u >> 16) & 1u);   // RNE
    return (unsigned short)(r >> 16);
}
__device__ __forceinline__ float bf2f(unsigned short h) {
    return __uint_as_float(((unsigned)h) << 16);
}
__device__ __forceinline__ float gru_h(float zs, float rs, float us, float vs,
                                       float bz, float br, float bu, float bv,
                                       float hprev) {
    float z = 1.f / (1.f + __expf(-(zs + bz)));
    float r = 1.f / (1.f + __expf(-(rs + br)));
    float n = 1.f - 2.f / (__expf(2.f * (us + bu + r * (vs + bv))) + 1.f);
    return (1.f - z) * n + z * hprev;
}

// ---------------- setup: VERBATIM round-1-proven W swizzle ----------------
// frag F = ((ct*48 + ks)*3 + g)*2 + s ; element: lane l, j ->
//   W[k = ks*32 + (l>>4)*8 + j][n = ct*16 + (l&15)]  (k<512: Wx, else Wh at k-512)
__global__ __launch_bounds__(256) void build_wsw(
    const float* __restrict__ Wzx, const float* __restrict__ Wzh,
    const float* __restrict__ Wrx, const float* __restrict__ Wrh,
    const float* __restrict__ Wnx, const float* __restrict__ Wnh,
    unsigned short* __restrict__ wsw)
{
    int idx = blockIdx.x * 256 + threadIdx.x;   // 589824 total = 2304*256
    int l = idx & 63;
    int rest = idx >> 6;
    int g = rest % 3; rest /= 3;
    int ks = rest % 48;
    int ct = rest / 48;
    if (ct >= 64) return;
    int k0 = ks * 32 + ((l >> 4) << 3);
    int n  = ct * 16 + (l & 15);
    const float* Wx = (g == 0) ? Wzx : (g == 1) ? Wrx : Wnx;
    const float* Wh = (g == 0) ? Wzh : (g == 1) ? Wrh : Wnh;
    const float* src = (k0 < Dd) ? (Wx + (size_t)k0 * Hh + n)
                                 : (Wh + (size_t)(k0 - Dd) * Hh + n);
    size_t base = ((((size_t)ct * 48 + ks) * 3 + g) * 2) * 512;
    unsigned short* hi = wsw + base + l * 8;
    unsigned short* lo = hi + 512;
    #pragma unroll
    for (int j = 0; j < 8; ++j) {
        float w = src[(size_t)j * Hh];
        unsigned short h16 = f2bf(w);
        hi[j] = h16;
        lo[j] = f2bf(w - bf2f(h16));
    }
}

// ---------------- per-rb-chain barrier: 64 blocks = 8 groups x GRP(8) ----------------
__device__ __forceinline__ void grid_barrier(unsigned* barr, int phase, int gidl, int tid) {
    __syncthreads();
    if (tid == 0) {
        __threadfence();   // device-scope release of this block's stores
        unsigned old = __hip_atomic_fetch_add(&barr[gidl * 16], 1u,
                                              __ATOMIC_ACQ_REL, __HIP_MEMORY_SCOPE_AGENT);
        if (old == (unsigned)(phase * GRP + (GRP - 1))) {    // last arriver in group
            unsigned m = __hip_atomic_fetch_add(&barr[128], 1u,
                                                __ATOMIC_ACQ_REL, __HIP_MEMORY_SCOPE_AGENT);
            if (m == (unsigned)(phase * 8 + 7)) {            // last of 8 groups
                __hip_atomic_fetch_add(&barr[144], 1u,
                                       __ATOMIC_RELEASE, __HIP_MEMORY_SCOPE_AGENT);
            }
        }
        while (__hip_atomic_load(&barr[144], __ATOMIC_ACQUIRE,
                                 __HIP_MEMORY_SCOPE_AGENT) < (unsigned)(phase + 1)) {
            __builtin_amdgcn_s_sleep(2);
        }
    }
    __syncthreads();
}

// ---------------- persistent GRU kernel: W-in-register, P-free ----------------
__global__ __launch_bounds__(512, 2) void gru_persist(
    const float* __restrict__ x,
    const float* __restrict__ bzx, const float* __restrict__ bzh,
    const float* __restrict__ brx, const float* __restrict__ brh,
    const float* __restrict__ bnx, const float* __restrict__ bnh,
    const unsigned short* __restrict__ wsw,
    unsigned short* __restrict__ hbuf,
    unsigned* __restrict__ bar,
    float* __restrict__ out)
{
    __shared__ float part[8][4][64][4];   // [wave][z,r,nx,nh][lane][q]  32 KB

    const int tid  = threadIdx.x;
    const int lane = tid & 63;
    const int wave = tid >> 6;            // 0..7
    const int bx   = blockIdx.x;
    const int rb   = bx >> 6;             // 0..3  (16-row chain)
    const int cb   = bx & 63;             // 0..63 (16-col tile)
    const int gidl = cb >> 3;             // barrier sub-group within chain
    unsigned* barr = bar + (rb << 8);     // 1 KB of counters per chain

    const int R0 = rb << 4;

    // ---- per-thread output element (threads 0..255 own the 16x16 tile) ----
    const int orow = tid >> 4;            // valid 0..15 for tid<256
    const int ocol = tid & 15;
    const int gcol = (cb << 4) + ocol;
    const int pl = ((orow & 12) << 2) | ocol;   // acc lane  = (orow>>2)*16 + ocol
    const int pq = orow & 3;                    // acc q-reg = orow & 3
    const float bz  = bzx[gcol] + bzh[gcol];
    const float brr = brx[gcol] + brh[gcol];
    const float bu  = bnx[gcol];          // bias OUTSIDE r-gate (x-side of n)
    const float bv  = bnh[gcol];          // bias INSIDE  r-gate (h-side of n)
    float hprev = 0.f;

    // ---- per-lane A-fragment addressing (row = lane&15, 8 contiguous k) ----
    const int arow  = lane & 15;
    const int acol8 = (lane >> 4) << 3;
    const float* xrow = x + (size_t)(R0 + arow) * (T_STEPS * Dd);

    // ---- one-time W preload: 36 frags -> 144 VGPR per wave ----
    // wave's ks set: x-side ks = wave*2 + {0,1}; h-side ks = 16 + wave*4 + {0..3}
    short8 wfr[36];
    #pragma unroll
    for (int i = 0; i < 6; ++i) {
        const int ks = (i < 2) ? (wave * 2 + i) : (16 + wave * 4 + (i - 2));
        const unsigned short* wp = wsw + (size_t)(cb * 48 + ks) * 3072 + lane * 8;
        #pragma unroll
        for (int f = 0; f < 6; ++f)       // zh, zl, rh, rl, nh, nl
            wfr[i * 6 + f] = *(const short8*)(wp + f * 512);
    }

    // ---- x fragments for t=0 ----
    short8 xa[2];
    #pragma unroll
    for (int i = 0; i < 2; ++i) {
        const float* xp = xrow + (wave * 64 + i * 32 + acol8);
        float4 v0 = *(const float4*)(xp);
        float4 v1 = *(const float4*)(xp + 4);
        short8 s;
        s[0] = (short)f2bf(v0.x); s[1] = (short)f2bf(v0.y);
        s[2] = (short)f2bf(v0.z); s[3] = (short)f2bf(v0.w);
        s[4] = (short)f2bf(v1.x); s[5] = (short)f2bf(v1.y);
        s[6] = (short)f2bf(v1.z); s[7] = (short)f2bf(v1.w);
        xa[i] = s;
    }

    for (int t = 0; t < T_STEPS; ++t) {
        // ---- issue h(t-1) fragment loads (parity (t-1)&1; zeros at t=0) ----
        const unsigned short* hrow = hbuf
            + ((size_t)((((t & 1) ^ 1) * Bb) + R0 + arow) << 10)
            + (wave << 7) + acol8;
        short8 hfr[4];
        #pragma unroll
        for (int j = 0; j < 4; ++j)
            hfr[j] = *(const short8*)(hrow + (j << 5));

        floatx4 zero4 = {0.f, 0.f, 0.f, 0.f};
        floatx4 aZ = zero4, aR = zero4, aNx = zero4, aNh = zero4;

        // ---- x-side MFMA (regs only; overlaps hfr load latency) ----
        #pragma unroll
        for (int i = 0; i < 2; ++i) {
            aZ  = __builtin_amdgcn_mfma_f32_16x16x32_bf16(xa[i], wfr[i*6+0], aZ,  0, 0, 0);
            aZ  = __builtin_amdgcn_mfma_f32_16x16x32_bf16(xa[i], wfr[i*6+1], aZ,  0, 0, 0);
            aR  = __builtin_amdgcn_mfma_f32_16x16x32_bf16(xa[i], wfr[i*6+2], aR,  0, 0, 0);
            aR  = __builtin_amdgcn_mfma_f32_16x16x32_bf16(xa[i], wfr[i*6+3], aR,  0, 0, 0);
            aNx = __builtin_amdgcn_mfma_f32_16x16x32_bf16(xa[i], wfr[i*6+4], aNx, 0, 0, 0);
            aNx = __builtin_amdgcn_mfma_f32_16x16x32_bf16(xa[i], wfr[i*6+5], aNx, 0, 0, 0);
        }

        // ---- prefetch x frags for t+1 into now-dead xa (hidden under h work) ----
        if (t + 1 < T_STEPS) {
            #pragma unroll
            for (int i = 0; i < 2; ++i) {
                const float* xp = xrow + (size_t)(t + 1) * Dd + (wave * 64 + i * 32 + acol8);
                float4 v0 = *(const float4*)(xp);
                float4 v1 = *(const float4*)(xp + 4);
                short8 s;
                s[0] = (short)f2bf(v0.x); s[1] = (short)f2bf(v0.y);
                s[2] = (short)f2bf(v0.z); s[3] = (short)f2bf(v0.w);
                s[4] = (short)f2bf(v1.x); s[5] = (short)f2bf(v1.y);
                s[6] = (short)f2bf(v1.z); s[7] = (short)f2bf(v1.w);
                xa[i] = s;
            }
        }

        // ---- h-side MFMA ----
        #pragma unroll
        for (int i = 2; i < 6; ++i) {
            const short8 a = hfr[i - 2];
            aZ  = __builtin_amdgcn_mfma_f32_16x16x32_bf16(a, wfr[i*6+0], aZ,  0, 0, 0);
            aZ  = __builtin_amdgcn_mfma_f32_16x16x32_bf16(a, wfr[i*6+1], aZ,  0, 0, 0);
            aR  = __builtin_amdgcn_mfma_f32_16x16x32_bf16(a, wfr[i*6+2], aR,  0, 0, 0);
            aR  = __builtin_amdgcn_mfma_f32_16x16x32_bf16(a, wfr[i*6+3], aR,  0, 0, 0);
            aNh = __builtin_amdgcn_mfma_f32_16x16x32_bf16(a, wfr[i*6+4], aNh, 0, 0, 0);
            aNh = __builtin_amdgcn_mfma_f32_16x16x32_bf16(a, wfr[i*6+5], aNh, 0, 0, 0);
        }

        // ---- cross-wave reduce in LDS ----
        *(floatx4*)&part[wave][0][lane][0] = aZ;
        *(floatx4*)&part[wave][1][lane][0] = aR;
        *(floatx4*)&part[wave][2][lane][0] = aNx;
        *(floatx4*)&part[wave][3][lane][0] = aNh;
        __syncthreads();

        if (tid < 256) {
            float zs = 0.f, rs = 0.f, us = 0.f, vs = 0.f;
            #pragma unroll
            for (int w = 0; w < 8; ++w) {
                zs += part[w][0][pl][pq];
                rs += part[w][1][pl][pq];
                us += part[w][2][pl][pq];
                vs += part[w][3][pl][pq];
            }
            float h = gru_h(zs, rs, us, vs, bz, brr, bu, bv, hprev);
            hprev = h;
            hbuf[((size_t)((t & 1) * Bb + R0 + orow) << 10) + gcol] = f2bf(h);
        }

        grid_barrier(barr, t, gidl, tid);
    }

    if (tid < 256)
        out[(size_t)(R0 + orow) * Hh + gcol] = hprev;
}

extern "C" void kernel_launch(void* const* d_in, const int* in_sizes, int n_in,
                              void* d_out, int out_size, void* d_ws, size_t ws_size,
                              hipStream_t stream) {
    const float* x   = (const float*)d_in[0];
    const float* Wzx = (const float*)d_in[1];
    const float* Wzh = (const float*)d_in[2];
    const float* Wrx = (const float*)d_in[3];
    const float* Wrh = (const float*)d_in[4];
    const float* Wnx = (const float*)d_in[5];
    const float* Wnh = (const float*)d_in[6];
    const float* bzx = (const float*)d_in[7];
    const float* bzh = (const float*)d_in[8];
    const float* brx = (const float*)d_in[9];
    const float* brh = (const float*)d_in[10];
    const float* bnx = (const float*)d_in[11];
    const float* bnh = (const float*)d_in[12];

    unsigned char* ws = (unsigned char*)d_ws;
    unsigned* bar = (unsigned*)ws;                               // 4 KB (4 chains x 1 KB)
    unsigned short* hbuf = (unsigned short*)(ws + 4096);         // 2 x 64 x 1024 bf16 = 256 KB
    unsigned short* wsw  = (unsigned short*)(ws + 4096 + 262144);// 18.9 MB
    // total ws use ~19.2 MB

    hipMemsetAsync(bar, 0, 4096, stream);
    hipMemsetAsync(hbuf, 0, (size_t)2 * Bb * Hh * sizeof(unsigned short), stream);

    build_wsw<<<2304, 256, 0, stream>>>(Wzx, Wzh, Wrx, Wrh, Wnx, Wnh, wsw);

    gru_persist<<<NBLK, 512, 0, stream>>>(x, bzx, bzh, brx, brh, bnx, bnh,
                                          wsw, hbuf, bar, (float*)d_out);
}

// Round 2
// 2054.442 us; speedup vs baseline: 9.6986x; 6.0041x over previous
//
#include <hip/hip_runtime.h>
#include <math.h>

// GRU B=64, T=512, D=512, H=1024 fp32.
// Round 8: fix the two counters R7 exposed.
//  (1) VGPR_Count=112 proved wfr[36] was NOT register-resident (needs 144) ->
//      W re-streamed from IF-cache every step (~75 MB/step). Now 36 NAMED short8
//      registers via macros; nothing runtime-indexed (rule #20).
//  (2) Barrier used agent acquire/release -> buffer_wbl2 per arrive and
//      buffer_inv per poll iteration (256 blocks thrashing all 8 L2s). Now:
//      h exchanged via inline-asm sc0 sc1 (IF-coherent, bypasses L2) loads/stores,
//      RELAXED agent atomics on a flat per-chain counter, ordering via
//      s_waitcnt vmcnt(0) + __syncthreads drain. No cache-wide maintenance ops.
//  (3) Split arrive/wait: x-side MFMA for t+1 + x prefetch for t+2 run in the
//      shadow after arrive; critical path = wait + h-load + 24 MFMA + reduce.
// build_wsw / frag maps / gru_h / parity double-buffer invariant verbatim R7.
#define T_STEPS 512
#define Bb 64
#define Dd 512
#define Hh 1024
#define NBLK 256

typedef __attribute__((ext_vector_type(8))) short short8;
typedef __attribute__((ext_vector_type(4))) float floatx4;
typedef __attribute__((ext_vector_type(4))) unsigned int uint4v;

__device__ __forceinline__ unsigned short f2bf(float f) {
    unsigned u = __float_as_uint(f);
    unsigned r = u + 0x7fffu + ((u >> 16) & 1u);   // RNE
    return (unsigned short)(r >> 16);
}
__device__ __forceinline__ float bf2f(unsigned short h) {
    return __uint_as_float(((unsigned)h) << 16);
}
__device__ __forceinline__ float gru_h(float zs, float rs, float us, float vs,
                                       float bz, float br, float bu, float bv,
                                       float hprev) {
    float z = 1.f / (1.f + __expf(-(zs + bz)));
    float r = 1.f / (1.f + __expf(-(rs + br)));
    float n = 1.f - 2.f / (__expf(2.f * (us + bu + r * (vs + bv))) + 1.f);
    return (1.f - z) * n + z * hprev;
}
__device__ __forceinline__ short8 cvt8(float4 a, float4 b) {
    short8 s;
    s[0] = (short)f2bf(a.x); s[1] = (short)f2bf(a.y);
    s[2] = (short)f2bf(a.z); s[3] = (short)f2bf(a.w);
    s[4] = (short)f2bf(b.x); s[5] = (short)f2bf(b.y);
    s[6] = (short)f2bf(b.z); s[7] = (short)f2bf(b.w);
    return s;
}

// ---------------- setup: VERBATIM round-1-proven W swizzle ----------------
__global__ __launch_bounds__(256) void build_wsw(
    const float* __restrict__ Wzx, const float* __restrict__ Wzh,
    const float* __restrict__ Wrx, const float* __restrict__ Wrh,
    const float* __restrict__ Wnx, const float* __restrict__ Wnh,
    unsigned short* __restrict__ wsw)
{
    int idx = blockIdx.x * 256 + threadIdx.x;   // 589824 total = 2304*256
    int l = idx & 63;
    int rest = idx >> 6;
    int g = rest % 3; rest /= 3;
    int ks = rest % 48;
    int ct = rest / 48;
    if (ct >= 64) return;
    int k0 = ks * 32 + ((l >> 4) << 3);
    int n  = ct * 16 + (l & 15);
    const float* Wx = (g == 0) ? Wzx : (g == 1) ? Wrx : Wnx;
    const float* Wh = (g == 0) ? Wzh : (g == 1) ? Wrh : Wnh;
    const float* src = (k0 < Dd) ? (Wx + (size_t)k0 * Hh + n)
                                 : (Wh + (size_t)(k0 - Dd) * Hh + n);
    size_t base = ((((size_t)ct * 48 + ks) * 3 + g) * 2) * 512;
    unsigned short* hi = wsw + base + l * 8;
    unsigned short* lo = hi + 512;
    #pragma unroll
    for (int j = 0; j < 8; ++j) {
        float w = src[(size_t)j * Hh];
        unsigned short h16 = f2bf(w);
        hi[j] = h16;
        lo[j] = f2bf(w - bf2f(h16));
    }
}

// W register set: 6 k-slices (i=0,1 x-side; i=2..5 h-side) x 6 frags each.
#define WDECL(i) short8 wzh##i, wzl##i, wrh##i, wrl##i, wnh##i, wnl##i
#define WLOAD(i, ksv) do { \
    const short8* wp = (const short8*)(wsw + (size_t)(cb * 48 + (ksv)) * 3072 + lane * 8); \
    wzh##i = wp[0];   wzl##i = wp[64]; \
    wrh##i = wp[128]; wrl##i = wp[192]; \
    wnh##i = wp[256]; wnl##i = wp[320]; } while (0)
#define XMFMA(i, av) do { \
    aZ  = __builtin_amdgcn_mfma_f32_16x16x32_bf16(av, wzh##i, aZ,  0, 0, 0); \
    aZ  = __builtin_amdgcn_mfma_f32_16x16x32_bf16(av, wzl##i, aZ,  0, 0, 0); \
    aR  = __builtin_amdgcn_mfma_f32_16x16x32_bf16(av, wrh##i, aR,  0, 0, 0); \
    aR  = __builtin_amdgcn_mfma_f32_16x16x32_bf16(av, wrl##i, aR,  0, 0, 0); \
    aNx = __builtin_amdgcn_mfma_f32_16x16x32_bf16(av, wnh##i, aNx, 0, 0, 0); \
    aNx = __builtin_amdgcn_mfma_f32_16x16x32_bf16(av, wnl##i, aNx, 0, 0, 0); } while (0)
#define HMFMA(i, av) do { \
    aZ  = __builtin_amdgcn_mfma_f32_16x16x32_bf16(av, wzh##i, aZ,  0, 0, 0); \
    aZ  = __builtin_amdgcn_mfma_f32_16x16x32_bf16(av, wzl##i, aZ,  0, 0, 0); \
    aR  = __builtin_amdgcn_mfma_f32_16x16x32_bf16(av, wrh##i, aR,  0, 0, 0); \
    aR  = __builtin_amdgcn_mfma_f32_16x16x32_bf16(av, wrl##i, aR,  0, 0, 0); \
    aNh = __builtin_amdgcn_mfma_f32_16x16x32_bf16(av, wnh##i, aNh, 0, 0, 0); \
    aNh = __builtin_amdgcn_mfma_f32_16x16x32_bf16(av, wnl##i, aNh, 0, 0, 0); } while (0)
#define LOADX(tt) do { const float* xp = xrow + (size_t)(tt) * Dd; \
    xf0 = *(const float4*)(xp);      xf1 = *(const float4*)(xp + 4); \
    xf2 = *(const float4*)(xp + 32); xf3 = *(const float4*)(xp + 36); } while (0)

// ---------------- persistent GRU: W-in-named-registers, relaxed barrier ----------------
__global__ __launch_bounds__(512, 2) void gru_persist(
    const float* __restrict__ x,
    const float* __restrict__ bzx, const float* __restrict__ bzh,
    const float* __restrict__ brx, const float* __restrict__ brh,
    const float* __restrict__ bnx, const float* __restrict__ bnh,
    const unsigned short* __restrict__ wsw,
    unsigned short* __restrict__ hbuf,
    unsigned* __restrict__ bar,
    float* __restrict__ out)
{
    __shared__ float part[8][4][64][4];   // [wave][z,r,nx,nh][lane][q]  32 KB

    const int tid  = threadIdx.x;
    const int lane = tid & 63;
    const int wave = tid >> 6;            // 0..7
    const int bx   = blockIdx.x;
    const int rb   = bx >> 6;             // 0..3  (16-row chain)
    const int cb   = bx & 63;             // 0..63 (16-col tile)
    unsigned* cnt  = bar + (rb << 6);     // flat per-chain counter, 256 B apart

    const int R0   = rb << 4;
    const int orow = tid >> 4;            // valid 0..15 for tid<256
    const int ocol = tid & 15;
    const int gcol = (cb << 4) + ocol;
    const int pl   = ((orow & 12) << 2) | ocol;
    const int pq   = orow & 3;
    const float bz  = bzx[gcol] + bzh[gcol];
    const float brr = brx[gcol] + brh[gcol];
    const float bu  = bnx[gcol];          // bias OUTSIDE r-gate (x-side of n)
    const float bv  = bnh[gcol];          // bias INSIDE  r-gate (h-side of n)
    float hprev = 0.f;

    const int arow  = lane & 15;
    const int acol8 = (lane >> 4) << 3;
    const float* xrow = x + (size_t)(R0 + arow) * (T_STEPS * Dd) + wave * 64 + acol8;

    // ---- one-time W preload into 36 NAMED registers (144 VGPR) ----
    WDECL(0); WDECL(1); WDECL(2); WDECL(3); WDECL(4); WDECL(5);
    WLOAD(0, wave * 2);      WLOAD(1, wave * 2 + 1);
    WLOAD(2, 16 + wave * 4); WLOAD(3, 17 + wave * 4);
    WLOAD(4, 18 + wave * 4); WLOAD(5, 19 + wave * 4);

    // ---- prologue: accX for t=0, prefetch x(1) ----
    float4 xf0, xf1, xf2, xf3;
    floatx4 aZ = {0.f,0.f,0.f,0.f}, aR = aZ, aNx = aZ;
    LOADX(0);
    {
        short8 xa0 = cvt8(xf0, xf1), xa1 = cvt8(xf2, xf3);
        XMFMA(0, xa0); XMFMA(1, xa1);
    }
    LOADX(1);

    for (int t = 0; t < T_STEPS; ++t) {
        // ---------- wait: all 64 chain blocks arrived t times ----------
        if (t) {
            __syncthreads();
            if (tid == 0) {
                const unsigned target = (unsigned)t * 64u;
                const unsigned* cp = cnt;
                unsigned v;
                for (;;) {
                    asm volatile("global_load_dword %0, %1, off sc0 sc1\n\t"
                                 "s_waitcnt vmcnt(0)"
                                 : "=&v"(v) : "v"(cp) : "memory");
                    if (v >= target) break;
                    __builtin_amdgcn_s_sleep(1);
                }
            }
            __syncthreads();
        }

        // ---------- h(t-1) coherent loads (bypass L2) ----------
        const unsigned short* hrow = hbuf
            + ((size_t)((((t & 1) ^ 1) * Bb) + R0 + arow) << 10)
            + (wave << 7) + acol8;
        uint4v h0, h1, h2, h3;
        asm volatile("global_load_dwordx4 %0, %1, off sc0 sc1"            : "=&v"(h0) : "v"(hrow) : "memory");
        asm volatile("global_load_dwordx4 %0, %1, off offset:64 sc0 sc1"  : "=&v"(h1) : "v"(hrow) : "memory");
        asm volatile("global_load_dwordx4 %0, %1, off offset:128 sc0 sc1" : "=&v"(h2) : "v"(hrow) : "memory");
        asm volatile("global_load_dwordx4 %0, %1, off offset:192 sc0 sc1" : "=&v"(h3) : "v"(hrow) : "memory");
        asm volatile("s_waitcnt vmcnt(0)" ::: "memory");
        __builtin_amdgcn_sched_barrier(0);   // rule #18: don't hoist MFMA above waitcnt

        // ---------- h-side MFMA (24) ----------
        floatx4 aNh = {0.f,0.f,0.f,0.f};
        {
            short8 a0 = __builtin_bit_cast(short8, h0);
            short8 a1 = __builtin_bit_cast(short8, h1);
            short8 a2 = __builtin_bit_cast(short8, h2);
            short8 a3 = __builtin_bit_cast(short8, h3);
            HMFMA(2, a0); HMFMA(3, a1); HMFMA(4, a2); HMFMA(5, a3);
        }

        // ---------- cross-wave reduce in LDS ----------
        *(floatx4*)&part[wave][0][lane][0] = aZ;
        *(floatx4*)&part[wave][1][lane][0] = aR;
        *(floatx4*)&part[wave][2][lane][0] = aNx;
        *(floatx4*)&part[wave][3][lane][0] = aNh;
        __syncthreads();

        if (tid < 256) {
            float zs = 0.f, rs = 0.f, us = 0.f, vs = 0.f;
            #pragma unroll
            for (int w = 0; w < 8; ++w) {
                zs += part[w][0][pl][pq];
                rs += part[w][1][pl][pq];
                us += part[w][2][pl][pq];
                vs += part[w][3][pl][pq];
            }
            float h = gru_h(zs, rs, us, vs, bz, brr, bu, bv, hprev);
            hprev = h;
            unsigned hv = (unsigned)f2bf(h);
            const unsigned short* hptr = hbuf
                + ((size_t)((t & 1) * Bb + R0 + orow) << 10) + gcol;
            asm volatile("global_store_short %0, %1, off sc0 sc1"
                         :: "v"(hptr), "v"(hv) : "memory");
        }
        // drain this wave's stores to the coherence point, then block-wide order
        asm volatile("s_waitcnt vmcnt(0)" ::: "memory");
        __syncthreads();

        // ---------- arrive (relaxed, fire-and-forget) ----------
        if (tid == 0)
            __hip_atomic_fetch_add(cnt, 1u, __ATOMIC_RELAXED, __HIP_MEMORY_SCOPE_AGENT);

        // ---------- shadow: x-side work for t+1 (off critical path) ----------
        if (t + 1 < T_STEPS) {
            floatx4 z4 = {0.f,0.f,0.f,0.f};
            aZ = z4; aR = z4; aNx = z4;
            short8 xa0 = cvt8(xf0, xf1), xa1 = cvt8(xf2, xf3);
            XMFMA(0, xa0); XMFMA(1, xa1);
            if (t + 2 < T_STEPS) LOADX(t + 2);
            __builtin_amdgcn_sched_barrier(0);   // keep shadow work here, not sunk past wait
        }
    }

    if (tid < 256)
        out[(size_t)(R0 + orow) * Hh + gcol] = hprev;
}

extern "C" void kernel_launch(void* const* d_in, const int* in_sizes, int n_in,
                              void* d_out, int out_size, void* d_ws, size_t ws_size,
                              hipStream_t stream) {
    const float* x   = (const float*)d_in[0];
    const float* Wzx = (const float*)d_in[1];
    const float* Wzh = (const float*)d_in[2];
    const float* Wrx = (const float*)d_in[3];
    const float* Wrh = (const float*)d_in[4];
    const float* Wnx = (const float*)d_in[5];
    const float* Wnh = (const float*)d_in[6];
    const float* bzx = (const float*)d_in[7];
    const float* bzh = (const float*)d_in[8];
    const float* brx = (const float*)d_in[9];
    const float* brh = (const float*)d_in[10];
    const float* bnx = (const float*)d_in[11];
    const float* bnh = (const float*)d_in[12];

    unsigned char* ws = (unsigned char*)d_ws;
    unsigned* bar = (unsigned*)ws;                               // 4 KB (4 chains x 256 B)
    unsigned short* hbuf = (unsigned short*)(ws + 4096);         // 2 x 64 x 1024 bf16 = 256 KB
    unsigned short* wsw  = (unsigned short*)(ws + 4096 + 262144);// 18.9 MB
    // total ws use ~19.2 MB

    hipMemsetAsync(bar, 0, 4096, stream);
    hipMemsetAsync(hbuf, 0, (size_t)2 * Bb * Hh * sizeof(unsigned short), stream);

    build_wsw<<<2304, 256, 0, stream>>>(Wzx, Wzh, Wrx, Wrh, Wnx, Wnh, wsw);

    gru_persist<<<NBLK, 512, 0, stream>>>(x, bzx, bzh, brx, brh, bnx, bnh,
                                          wsw, hbuf, bar, (float*)d_out);
}

// Round 3
// 2049.226 us; speedup vs baseline: 9.7233x; 1.0025x over previous
//
#include <hip/hip_runtime.h>
#include <math.h>

// GRU B=64, T=512, D=512, H=1024 fp32.
// Round 9: VGPR_Count=108 proved the compiler sank the W loads back into the
// t-loop (ordinary loads may be re-executed) -> 295 KB/block of W re-streamed
// from L2/IF every step. Fix: 36 asm-volatile global_load_dwordx4 into NAMED
// uint4v registers before the loop -- volatile asm cannot be sunk, duplicated,
// or rematerialized, so W is pinned in VGPRs (144) for the whole kernel.
// Everything else verbatim R8 (proven): sc0sc1 coherent h path, relaxed flat
// counter barrier, split arrive/wait with shadow x-side MFMA for t+1.
#define T_STEPS 512
#define Bb 64
#define Dd 512
#define Hh 1024
#define NBLK 256

typedef __attribute__((ext_vector_type(8))) short short8;
typedef __attribute__((ext_vector_type(4))) float floatx4;
typedef __attribute__((ext_vector_type(4))) unsigned int uint4v;

__device__ __forceinline__ unsigned short f2bf(float f) {
    unsigned u = __float_as_uint(f);
    unsigned r = u + 0x7fffu + ((u >> 16) & 1u);   // RNE
    return (unsigned short)(r >> 16);
}
__device__ __forceinline__ float bf2f(unsigned short h) {
    return __uint_as_float(((unsigned)h) << 16);
}
__device__ __forceinline__ float gru_h(float zs, float rs, float us, float vs,
                                       float bz, float br, float bu, float bv,
                                       float hprev) {
    float z = 1.f / (1.f + __expf(-(zs + bz)));
    float r = 1.f / (1.f + __expf(-(rs + br)));
    float n = 1.f - 2.f / (__expf(2.f * (us + bu + r * (vs + bv))) + 1.f);
    return (1.f - z) * n + z * hprev;
}
__device__ __forceinline__ short8 cvt8(float4 a, float4 b) {
    short8 s;
    s[0] = (short)f2bf(a.x); s[1] = (short)f2bf(a.y);
    s[2] = (short)f2bf(a.z); s[3] = (short)f2bf(a.w);
    s[4] = (short)f2bf(b.x); s[5] = (short)f2bf(b.y);
    s[6] = (short)f2bf(b.z); s[7] = (short)f2bf(b.w);
    return s;
}

// ---------------- setup: VERBATIM round-1-proven W swizzle ----------------
__global__ __launch_bounds__(256) void build_wsw(
    const float* __restrict__ Wzx, const float* __restrict__ Wzh,
    const float* __restrict__ Wrx, const float* __restrict__ Wrh,
    const float* __restrict__ Wnx, const float* __restrict__ Wnh,
    unsigned short* __restrict__ wsw)
{
    int idx = blockIdx.x * 256 + threadIdx.x;   // 589824 total = 2304*256
    int l = idx & 63;
    int rest = idx >> 6;
    int g = rest % 3; rest /= 3;
    int ks = rest % 48;
    int ct = rest / 48;
    if (ct >= 64) return;
    int k0 = ks * 32 + ((l >> 4) << 3);
    int n  = ct * 16 + (l & 15);
    const float* Wx = (g == 0) ? Wzx : (g == 1) ? Wrx : Wnx;
    const float* Wh = (g == 0) ? Wzh : (g == 1) ? Wrh : Wnh;
    const float* src = (k0 < Dd) ? (Wx + (size_t)k0 * Hh + n)
                                 : (Wh + (size_t)(k0 - Dd) * Hh + n);
    size_t base = ((((size_t)ct * 48 + ks) * 3 + g) * 2) * 512;
    unsigned short* hi = wsw + base + l * 8;
    unsigned short* lo = hi + 512;
    #pragma unroll
    for (int j = 0; j < 8; ++j) {
        float w = src[(size_t)j * Hh];
        unsigned short h16 = f2bf(w);
        hi[j] = h16;
        lo[j] = f2bf(w - bf2f(h16));
    }
}

// W register set: 6 k-slices (i=0,1 x-side; i=2..5 h-side) x 6 frags each.
// Loaded once via asm volatile (un-sinkable, un-rematerializable) -> pinned.
#define WDECL(i) uint4v uzh##i, uzl##i, urh##i, url##i, unh##i, unl##i
#define WLOADA(i, ksv) do { \
    const unsigned short* wp = wsw + (size_t)(cb * 48 + (ksv)) * 3072 + lane * 8; \
    asm volatile("global_load_dwordx4 %0, %1, off" : "=&v"(uzh##i) : "v"(wp)        ); \
    asm volatile("global_load_dwordx4 %0, %1, off" : "=&v"(uzl##i) : "v"(wp + 512)  ); \
    asm volatile("global_load_dwordx4 %0, %1, off" : "=&v"(urh##i) : "v"(wp + 1024) ); \
    asm volatile("global_load_dwordx4 %0, %1, off" : "=&v"(url##i) : "v"(wp + 1536) ); \
    asm volatile("global_load_dwordx4 %0, %1, off" : "=&v"(unh##i) : "v"(wp + 2048) ); \
    asm volatile("global_load_dwordx4 %0, %1, off" : "=&v"(unl##i) : "v"(wp + 2560) ); \
} while (0)
#define WS(name) __builtin_bit_cast(short8, name)
#define XMFMA(i, av) do { \
    aZ  = __builtin_amdgcn_mfma_f32_16x16x32_bf16(av, WS(uzh##i), aZ,  0, 0, 0); \
    aZ  = __builtin_amdgcn_mfma_f32_16x16x32_bf16(av, WS(uzl##i), aZ,  0, 0, 0); \
    aR  = __builtin_amdgcn_mfma_f32_16x16x32_bf16(av, WS(urh##i), aR,  0, 0, 0); \
    aR  = __builtin_amdgcn_mfma_f32_16x16x32_bf16(av, WS(url##i), aR,  0, 0, 0); \
    aNx = __builtin_amdgcn_mfma_f32_16x16x32_bf16(av, WS(unh##i), aNx, 0, 0, 0); \
    aNx = __builtin_amdgcn_mfma_f32_16x16x32_bf16(av, WS(unl##i), aNx, 0, 0, 0); } while (0)
#define HMFMA(i, av) do { \
    aZ  = __builtin_amdgcn_mfma_f32_16x16x32_bf16(av, WS(uzh##i), aZ,  0, 0, 0); \
    aZ  = __builtin_amdgcn_mfma_f32_16x16x32_bf16(av, WS(uzl##i), aZ,  0, 0, 0); \
    aR  = __builtin_amdgcn_mfma_f32_16x16x32_bf16(av, WS(urh##i), aR,  0, 0, 0); \
    aR  = __builtin_amdgcn_mfma_f32_16x16x32_bf16(av, WS(url##i), aR,  0, 0, 0); \
    aNh = __builtin_amdgcn_mfma_f32_16x16x32_bf16(av, WS(unh##i), aNh, 0, 0, 0); \
    aNh = __builtin_amdgcn_mfma_f32_16x16x32_bf16(av, WS(unl##i), aNh, 0, 0, 0); } while (0)
#define LOADX(tt) do { const float* xp = xrow + (size_t)(tt) * Dd; \
    xf0 = *(const float4*)(xp);      xf1 = *(const float4*)(xp + 4); \
    xf2 = *(const float4*)(xp + 32); xf3 = *(const float4*)(xp + 36); } while (0)

// ---------------- persistent GRU: W pinned in registers, relaxed barrier ----------------
__global__ __launch_bounds__(512, 2) void gru_persist(
    const float* __restrict__ x,
    const float* __restrict__ bzx, const float* __restrict__ bzh,
    const float* __restrict__ brx, const float* __restrict__ brh,
    const float* __restrict__ bnx, const float* __restrict__ bnh,
    const unsigned short* __restrict__ wsw,
    unsigned short* __restrict__ hbuf,
    unsigned* __restrict__ bar,
    float* __restrict__ out)
{
    __shared__ float part[8][4][64][4];   // [wave][z,r,nx,nh][lane][q]  32 KB

    const int tid  = threadIdx.x;
    const int lane = tid & 63;
    const int wave = tid >> 6;            // 0..7
    const int bx   = blockIdx.x;
    const int rb   = bx >> 6;             // 0..3  (16-row chain)
    const int cb   = bx & 63;             // 0..63 (16-col tile)
    unsigned* cnt  = bar + (rb << 6);     // flat per-chain counter, 256 B apart

    const int R0   = rb << 4;
    const int orow = tid >> 4;            // valid 0..15 for tid<256
    const int ocol = tid & 15;
    const int gcol = (cb << 4) + ocol;
    const int pl   = ((orow & 12) << 2) | ocol;
    const int pq   = orow & 3;
    const float bz  = bzx[gcol] + bzh[gcol];
    const float brr = brx[gcol] + brh[gcol];
    const float bu  = bnx[gcol];          // bias OUTSIDE r-gate (x-side of n)
    const float bv  = bnh[gcol];          // bias INSIDE  r-gate (h-side of n)
    float hprev = 0.f;

    const int arow  = lane & 15;
    const int acol8 = (lane >> 4) << 3;
    const float* xrow = x + (size_t)(R0 + arow) * (T_STEPS * Dd) + wave * 64 + acol8;

    // ---- one-time W preload: 36 asm-volatile loads -> pinned 144 VGPR ----
    WDECL(0); WDECL(1); WDECL(2); WDECL(3); WDECL(4); WDECL(5);
    WLOADA(0, wave * 2);      WLOADA(1, wave * 2 + 1);
    WLOADA(2, 16 + wave * 4); WLOADA(3, 17 + wave * 4);
    WLOADA(4, 18 + wave * 4); WLOADA(5, 19 + wave * 4);
    asm volatile("s_waitcnt vmcnt(0)" ::: "memory");
    __builtin_amdgcn_sched_barrier(0);

    // ---- prologue: accX for t=0, prefetch x(1) ----
    float4 xf0, xf1, xf2, xf3;
    floatx4 aZ = {0.f,0.f,0.f,0.f}, aR = aZ, aNx = aZ;
    LOADX(0);
    {
        short8 xa0 = cvt8(xf0, xf1), xa1 = cvt8(xf2, xf3);
        XMFMA(0, xa0); XMFMA(1, xa1);
    }
    LOADX(1);

    for (int t = 0; t < T_STEPS; ++t) {
        // ---------- wait: all 64 chain blocks arrived t times ----------
        if (t) {
            __syncthreads();
            if (tid == 0) {
                const unsigned target = (unsigned)t * 64u;
                const unsigned* cp = cnt;
                unsigned v;
                for (;;) {
                    asm volatile("global_load_dword %0, %1, off sc0 sc1\n\t"
                                 "s_waitcnt vmcnt(0)"
                                 : "=&v"(v) : "v"(cp) : "memory");
                    if (v >= target) break;
                    __builtin_amdgcn_s_sleep(1);
                }
            }
            __syncthreads();
        }

        // ---------- h(t-1) coherent loads (bypass L2) ----------
        const unsigned short* hrow = hbuf
            + ((size_t)((((t & 1) ^ 1) * Bb) + R0 + arow) << 10)
            + (wave << 7) + acol8;
        uint4v h0, h1, h2, h3;
        asm volatile("global_load_dwordx4 %0, %1, off sc0 sc1"            : "=&v"(h0) : "v"(hrow) : "memory");
        asm volatile("global_load_dwordx4 %0, %1, off offset:64 sc0 sc1"  : "=&v"(h1) : "v"(hrow) : "memory");
        asm volatile("global_load_dwordx4 %0, %1, off offset:128 sc0 sc1" : "=&v"(h2) : "v"(hrow) : "memory");
        asm volatile("global_load_dwordx4 %0, %1, off offset:192 sc0 sc1" : "=&v"(h3) : "v"(hrow) : "memory");
        asm volatile("s_waitcnt vmcnt(0)" ::: "memory");
        __builtin_amdgcn_sched_barrier(0);   // rule #18: don't hoist MFMA above waitcnt

        // ---------- h-side MFMA (24) ----------
        floatx4 aNh = {0.f,0.f,0.f,0.f};
        {
            short8 a0 = __builtin_bit_cast(short8, h0);
            short8 a1 = __builtin_bit_cast(short8, h1);
            short8 a2 = __builtin_bit_cast(short8, h2);
            short8 a3 = __builtin_bit_cast(short8, h3);
            HMFMA(2, a0); HMFMA(3, a1); HMFMA(4, a2); HMFMA(5, a3);
        }

        // ---------- cross-wave reduce in LDS ----------
        *(floatx4*)&part[wave][0][lane][0] = aZ;
        *(floatx4*)&part[wave][1][lane][0] = aR;
        *(floatx4*)&part[wave][2][lane][0] = aNx;
        *(floatx4*)&part[wave][3][lane][0] = aNh;
        __syncthreads();

        if (tid < 256) {
            float zs = 0.f, rs = 0.f, us = 0.f, vs = 0.f;
            #pragma unroll
            for (int w = 0; w < 8; ++w) {
                zs += part[w][0][pl][pq];
                rs += part[w][1][pl][pq];
                us += part[w][2][pl][pq];
                vs += part[w][3][pl][pq];
            }
            float h = gru_h(zs, rs, us, vs, bz, brr, bu, bv, hprev);
            hprev = h;
            unsigned hv = (unsigned)f2bf(h);
            const unsigned short* hptr = hbuf
                + ((size_t)((t & 1) * Bb + R0 + orow) << 10) + gcol;
            asm volatile("global_store_short %0, %1, off sc0 sc1"
                         :: "v"(hptr), "v"(hv) : "memory");
        }
        // drain this wave's stores to the coherence point, then block-wide order
        asm volatile("s_waitcnt vmcnt(0)" ::: "memory");
        __syncthreads();

        // ---------- arrive (relaxed, fire-and-forget) ----------
        if (tid == 0)
            __hip_atomic_fetch_add(cnt, 1u, __ATOMIC_RELAXED, __HIP_MEMORY_SCOPE_AGENT);

        // ---------- shadow: x-side work for t+1 (off critical path) ----------
        if (t + 1 < T_STEPS) {
            floatx4 z4 = {0.f,0.f,0.f,0.f};
            aZ = z4; aR = z4; aNx = z4;
            short8 xa0 = cvt8(xf0, xf1), xa1 = cvt8(xf2, xf3);
            XMFMA(0, xa0); XMFMA(1, xa1);
            if (t + 2 < T_STEPS) LOADX(t + 2);
            __builtin_amdgcn_sched_barrier(0);   // keep shadow work here, not sunk past wait
        }
    }

    if (tid < 256)
        out[(size_t)(R0 + orow) * Hh + gcol] = hprev;
}

extern "C" void kernel_launch(void* const* d_in, const int* in_sizes, int n_in,
                              void* d_out, int out_size, void* d_ws, size_t ws_size,
                              hipStream_t stream) {
    const float* x   = (const float*)d_in[0];
    const float* Wzx = (const float*)d_in[1];
    const float* Wzh = (const float*)d_in[2];
    const float* Wrx = (const float*)d_in[3];
    const float* Wrh = (const float*)d_in[4];
    const float* Wnx = (const float*)d_in[5];
    const float* Wnh = (const float*)d_in[6];
    const float* bzx = (const float*)d_in[7];
    const float* bzh = (const float*)d_in[8];
    const float* brx = (const float*)d_in[9];
    const float* brh = (const float*)d_in[10];
    const float* bnx = (const float*)d_in[11];
    const float* bnh = (const float*)d_in[12];

    unsigned char* ws = (unsigned char*)d_ws;
    unsigned* bar = (unsigned*)ws;                               // 4 KB (4 chains x 256 B)
    unsigned short* hbuf = (unsigned short*)(ws + 4096);         // 2 x 64 x 1024 bf16 = 256 KB
    unsigned short* wsw  = (unsigned short*)(ws + 4096 + 262144);// 18.9 MB
    // total ws use ~19.2 MB

    hipMemsetAsync(bar, 0, 4096, stream);
    hipMemsetAsync(hbuf, 0, (size_t)2 * Bb * Hh * sizeof(unsigned short), stream);

    build_wsw<<<2304, 256, 0, stream>>>(Wzx, Wzh, Wrx, Wrh, Wnx, Wnh, wsw);

    gru_persist<<<NBLK, 512, 0, stream>>>(x, bzx, bzh, brx, brh, bnx, bnh,
                                          wsw, hbuf, bar, (float*)d_out);
}